// Round 1
// 826.872 us; speedup vs baseline: 1.0555x; 1.0555x over previous
//
#include <hip/hip_runtime.h>

#define BATCH  262144
#define N_FEAT 256
#define N_INT  255
#define N_LEAF 256
#define ROWS   32
#define THREADS 256
#define NSUB   8   // subtrees rooted at depth 3

// Fully-unrolled DFS over one depth-3-rooted subtree (local depths J=0..4 <->
// global depths 3..7). prefix is compile-time-propagated per inlined call
// site, so all LDS offsets fold to ds_read immediates off a runtime base.
template<int J>
__device__ __forceinline__ float dfs(const float* __restrict__ row,
                                     int s, int prefix, float p,
                                     const float* __restrict__ leaf) {
  if constexpr (J == 5) {
    return p * leaf[(s << 5) + prefix];          // leaf index = b0..b7 = (s<<5)|prefix
  } else {
    int node = ((1 << (J + 3)) - 1) + (s << J) + prefix;  // heap index, depth J+3
    float w = row[node];
    return dfs<J + 1>(row, s, (prefix << 1),     p * (1.0f - w), leaf)
         + dfs<J + 1>(row, s, (prefix << 1) | 1, p * w,          leaf);
  }
}

__global__ __launch_bounds__(THREADS, 4) void sdt_kernel(
    const float* __restrict__ x,
    const float* __restrict__ split_cond,
    const float* __restrict__ u,
    const float* __restrict__ leaf_values,
    const int* __restrict__ split_idx,
    float* __restrict__ out)
{
  // 32 rows x 257 (pad +1: phase-2 reads become (r + node) % 32 -> each bank
  // serves exactly 2 lanes of the wave = free 2-way)
  __shared__ float s_w[ROWS][N_FEAT + 1];   // 32.9 KB
  __shared__ float s_leaf[N_LEAF];          //  1.0 KB
  __shared__ float s_acc[NSUB][ROWS];       //  1.0 KB   -> ~35 KB total, 4 blocks/CU

  const int tid  = threadIdx.x;
  const int row0 = blockIdx.x * ROWS;

  s_leaf[tid] = leaf_values[tid];

  // ---- Phase 1: thread = node, loop over the tile's 32 rows. ----
  // u loads: lanes cover contiguous float2s -> 512 B/wave coalesced.
  // x gather: whole block shares one 1KB x row per iter -> L1-resident.
  // cond/idx: read once per thread -> registers, no LDS round-trip.
  if (tid < N_INT) {
    const float sc = split_cond[tid];
    const int   si = split_idx[tid];
    const float2* up = (const float2*)(u + (size_t)row0 * (2 * N_INT)) + tid;
    const float*  xp = x + (size_t)row0 * N_FEAT + si;
    #pragma unroll 16
    for (int r = 0; r < ROWS; ++r) {
      float2 uv = up[(size_t)r * N_INT];
      float  xv = xp[(size_t)r * N_FEAT];
      float u0 = fminf(fmaxf(uv.x, 1e-10f), 1.0f);
      float u1 = fminf(fmaxf(uv.y, 1e-10f), 1.0f);
      float g0 = -__logf(-__logf(u0));          // Gumbel(0,1)
      float g1 = -__logf(-__logf(u1));
      float z  = (xv - sc) + (g0 - g1);
      float w  = 1.0f / (1.0f + __expf(-z));    // sigmoid
      s_w[r][tid] = w;
    }
  }
  __syncthreads();

  // ---- Phase 2: thread = (subtree s in 0..7, row r in 0..31). ----
  // Path factors for depths 0..2, then DFS over the depth-3 subtree.
  {
    const int s = tid >> 5;        // half-wave-uniform
    const int r = tid & 31;
    const float* row = &s_w[r][0];
    float w0 = row[0];                  // depth 0, b0 = (s>>2)&1
    float f0 = (s & 4) ? w0 : (1.0f - w0);
    float w1 = row[1 + (s >> 2)];       // depth 1, b1 = (s>>1)&1
    float f1 = (s & 2) ? w1 : (1.0f - w1);
    float w2 = row[3 + (s >> 1)];       // depth 2, b2 = s&1
    float f2 = (s & 1) ? w2 : (1.0f - w2);
    s_acc[s][r] = dfs<0>(row, s, 0, (f0 * f1) * f2, s_leaf);
  }
  __syncthreads();

  if (tid < ROWS) {
    float v = ((s_acc[0][tid] + s_acc[1][tid]) + (s_acc[2][tid] + s_acc[3][tid]))
            + ((s_acc[4][tid] + s_acc[5][tid]) + (s_acc[6][tid] + s_acc[7][tid]));
    out[row0 + tid] = v;
  }
}

extern "C" void kernel_launch(void* const* d_in, const int* in_sizes, int n_in,
                              void* d_out, int out_size, void* d_ws, size_t ws_size,
                              hipStream_t stream) {
  const float* x           = (const float*)d_in[0];
  const float* split_cond  = (const float*)d_in[1];
  const float* u           = (const float*)d_in[2];
  const float* leaf_values = (const float*)d_in[3];
  const int*   split_idx   = (const int*)d_in[4];
  float*       out         = (float*)d_out;

  sdt_kernel<<<dim3(BATCH / ROWS), dim3(THREADS), 0, stream>>>(
      x, split_cond, u, leaf_values, split_idx, out);
}